// Round 1
// baseline (204.857 us; speedup 1.0000x reference)
//
#include <hip/hip_runtime.h>

typedef _Float16 half_t;
typedef half_t f16x8 __attribute__((ext_vector_type(8)));
typedef float f32x4 __attribute__((ext_vector_type(4)));

#define LOG2E 1.44269504088896340736f

// Problem dims (fixed)
#define NROWS 65536
#define DIN   64
#define NCTRS 1024
#define DOUT  256

// Workspace layout (bytes)
#define CSWZ_BYTES (32 * 2 * 2 * 64 * 16)   // 131072: QK B-frags [c][ct][kt][lane][8 halves]
#define VSWZ_BYTES (32 * 18 * 64 * 16)      // 589824: PV B-frags [c][slot 0..17][lane][8]
#define CSWZ_OFF 0
#define VSWZ_OFF (CSWZ_OFF + CSWZ_BYTES)
#define CSQ_OFF  (VSWZ_OFF + VSWZ_BYTES)    // 720896: 1024 floats = csq[k]*LOG2E

// ---------------------------------------------------------------------------
// Precompute: swizzle ctrs (fp16 QK B-frags), values^T (fp16 PV B-frags with
// an extra all-ones column tile per half for the row-sum trick), csq2.
// Fragment layout (A and B symmetric, verified m120/m93):
//   lane holds  [idx = lane&15][k = 8*(lane>>4) + j], j = 0..7  (16B contiguous)
// ---------------------------------------------------------------------------
__global__ __launch_bounds__(256) void precompute_kernel(
    const float* __restrict__ ctrs, const float* __restrict__ values,
    const float* __restrict__ s, char* __restrict__ ws) {
  half_t* Cswz = (half_t*)(ws + CSWZ_OFF);
  half_t* Vswz = (half_t*)(ws + VSWZ_OFF);
  float* csq2 = (float*)(ws + CSQ_OFF);
  const int bid = blockIdx.x, tid = threadIdx.x;
  const int w = tid >> 6, l = tid & 63, l4 = l >> 4, lm = l & 15;

  if (bid < 32) {
    // Cswz: 128 frags, one per wave. frag fid = c*4 + ct*2 + kt
    int fid = bid * 4 + w;
    int c = fid >> 2, ct = (fid >> 1) & 1, kt = fid & 1;
    int center = c * 32 + ct * 16 + lm;       // B-operand n index
    int din = kt * 32 + l4 * 8;               // k index base
    const float* src = ctrs + center * DIN + din;
    f16x8 v;
#pragma unroll
    for (int j = 0; j < 8; ++j) v[j] = (half_t)src[j];
    *(f16x8*)(Cswz + fid * 512 + l * 8) = v;
  } else if (bid < 176) {
    // Vswz: 576 frags. layout per chunk c: slots 0..7 = out-cols 0..127,
    // slot 8 = ones, slots 9..16 = out-cols 128..255, slot 17 = ones.
    int fid = (bid - 32) * 4 + w;
    int c = fid / 18, slot = fid % 18;
    f16x8 v;
    if (slot == 8 || slot == 17) {
#pragma unroll
      for (int j = 0; j < 8; ++j) v[j] = (lm == 0) ? (half_t)1.0f : (half_t)0.0f;
    } else {
      int ct = (slot < 8) ? slot : (slot - 1);
      int col = ct * 16 + lm;                 // B-operand n = output column
#pragma unroll
      for (int j = 0; j < 8; ++j) {
        int center = c * 32 + l4 * 8 + j;     // k = center-within-chunk
        v[j] = (half_t)values[center * DOUT + col];
      }
    }
    *(f16x8*)(Vswz + fid * 512 + l * 8) = v;
  } else {
    // csq2[k] = (sum_d ctrs[k,d]^2 * s[d]) * LOG2E
    int k = (bid - 176) * 256 + tid;
    float acc = 0.0f;
    for (int d = 0; d < DIN; ++d) {
      float cv = ctrs[k * DIN + d];
      acc = fmaf(cv * cv, s[d], acc);
    }
    csq2[k] = acc * LOG2E;
  }
}

// ---------------------------------------------------------------------------
// Main fused kernel: block = 256 rows x 128 out-cols (4 waves, 64 rows each),
// online softmax over 32 chunks of 32 centers. scores = (2*cross - csq)*log2e
// (x^2 term cancels in softmax). Row-sum via MFMA ones-column.
// ---------------------------------------------------------------------------
__global__ __launch_bounds__(256, 2) void attn_kernel(
    const float* __restrict__ x, const float* __restrict__ s,
    const char* __restrict__ ws, float* __restrict__ out) {
  const half_t* Cswz = (const half_t*)(ws + CSWZ_OFF);
  const half_t* Vswz = (const half_t*)(ws + VSWZ_OFF);
  const float* csq2 = (const float*)(ws + CSQ_OFF);

  __shared__ half_t Alds[4 * 4 * 2 * 64 * 8];  // per-wave A frags: 32768 B
  __shared__ half_t Vlds[9 * 64 * 8];          // V chunk frags:     9216 B
  __shared__ half_t Plds[4 * 64 * 40];         // per-wave P (pad40): 20480 B

  const int tid = threadIdx.x;
  const int w = tid >> 6, l = tid & 63, l4 = l >> 4, lm = l & 15;
  const int rowg = blockIdx.x >> 1, hb = blockIdx.x & 1;  // hb = col half
  const int rowbase = rowg * 256 + w * 64;

  // ---- stage A fragments (x*s -> f16), per-wave private, no barrier needed
#pragma unroll
  for (int rt = 0; rt < 4; ++rt) {
#pragma unroll
    for (int kt = 0; kt < 2; ++kt) {
      int row = rowbase + rt * 16 + lm;        // A-operand m index
      int din = kt * 32 + l4 * 8;
      const float* src = x + row * DIN + din;
      f16x8 a;
#pragma unroll
      for (int j = 0; j < 8; ++j) a[j] = (half_t)(src[j] * s[din + j]);
      *(f16x8*)(Alds + (((w * 4 + rt) * 2 + kt) * 64 + l) * 8) = a;
    }
  }

  // ---- accumulators
  f32x4 O[4][8];
  f32x4 L[4];
  float m[4][4];
#pragma unroll
  for (int rt = 0; rt < 4; ++rt) {
    L[rt] = (f32x4){0.f, 0.f, 0.f, 0.f};
#pragma unroll
    for (int ct = 0; ct < 8; ++ct) O[rt][ct] = (f32x4){0.f, 0.f, 0.f, 0.f};
#pragma unroll
    for (int j = 0; j < 4; ++j) m[rt][j] = -1e30f;
  }

  for (int c = 0; c < 32; ++c) {
    __syncthreads();  // protect previous chunk's Vlds reads
    {   // stage 9 KB of V frags (this block's col-half + ones tile)
      const float4* src = (const float4*)(Vswz + (c * 18 + 9 * hb) * 512);
      float4* dst = (float4*)Vlds;
      for (int i = tid; i < 576; i += 256) dst[i] = src[i];
    }
    __syncthreads();

    // ---- QK: S[64 rows][32 centers] per wave, K = DIN = 64 (2 ksteps)
    float s2[2][4][4];
#pragma unroll
    for (int ct = 0; ct < 2; ++ct) {
      int fid = c * 4 + ct * 2;
      f16x8 b0 = *(const f16x8*)(Cswz + (fid + 0) * 512 + l * 8);
      f16x8 b1 = *(const f16x8*)(Cswz + (fid + 1) * 512 + l * 8);
      float cs = csq2[c * 32 + ct * 16 + lm];  // col of this lane in C-layout
#pragma unroll
      for (int rt = 0; rt < 4; ++rt) {
        f16x8 a0 = *(const f16x8*)(Alds + (((w * 4 + rt) * 2 + 0) * 64 + l) * 8);
        f16x8 a1 = *(const f16x8*)(Alds + (((w * 4 + rt) * 2 + 1) * 64 + l) * 8);
        f32x4 acc = {0.f, 0.f, 0.f, 0.f};
        acc = __builtin_amdgcn_mfma_f32_16x16x32_f16(a0, b0, acc, 0, 0, 0);
        acc = __builtin_amdgcn_mfma_f32_16x16x32_f16(a1, b1, acc, 0, 0, 0);
#pragma unroll
        for (int j = 0; j < 4; ++j)
          s2[ct][rt][j] = fmaf(acc[j], 2.0f * LOG2E, -cs);  // score * log2e
      }
    }

    // ---- online softmax (in-register; rows live in 16-lane groups)
#pragma unroll
    for (int rt = 0; rt < 4; ++rt) {
#pragma unroll
      for (int j = 0; j < 4; ++j) {
        float mc = fmaxf(s2[0][rt][j], s2[1][rt][j]);
        mc = fmaxf(mc, __shfl_xor(mc, 1));
        mc = fmaxf(mc, __shfl_xor(mc, 2));
        mc = fmaxf(mc, __shfl_xor(mc, 4));
        mc = fmaxf(mc, __shfl_xor(mc, 8));
        float mn = fmaxf(m[rt][j], mc);
        float al = __builtin_amdgcn_exp2f(m[rt][j] - mn);
        m[rt][j] = mn;
        L[rt][j] *= al;
#pragma unroll
        for (int ct = 0; ct < 8; ++ct) O[rt][ct][j] *= al;
        int prow = rt * 16 + l4 * 4 + j;       // row in C-layout
#pragma unroll
        for (int ct = 0; ct < 2; ++ct) {
          float p = __builtin_amdgcn_exp2f(s2[ct][rt][j] - mn);
          Plds[(w * 64 + prow) * 40 + ct * 16 + lm] = (half_t)p;
        }
      }
    }

    // ---- PV: O += P @ V (K = 32 centers, 1 kstep); slot 8 = ones -> L
    f16x8 pa[4];
#pragma unroll
    for (int rt = 0; rt < 4; ++rt)
      pa[rt] = *(const f16x8*)(Plds + (w * 64 + rt * 16 + lm) * 40 + l4 * 8);
#pragma unroll
    for (int slot = 0; slot < 9; ++slot) {
      f16x8 vb = *(const f16x8*)(Vlds + (slot * 64 + l) * 8);
      if (slot < 8) {
#pragma unroll
        for (int rt = 0; rt < 4; ++rt)
          O[rt][slot] = __builtin_amdgcn_mfma_f32_16x16x32_f16(pa[rt], vb, O[rt][slot], 0, 0, 0);
      } else {
#pragma unroll
        for (int rt = 0; rt < 4; ++rt)
          L[rt] = __builtin_amdgcn_mfma_f32_16x16x32_f16(pa[rt], vb, L[rt], 0, 0, 0);
      }
    }
  }

  // ---- epilogue: divide by row-sum (held in col 0 of L tile = lane lm==0)
#pragma unroll
  for (int rt = 0; rt < 4; ++rt) {
#pragma unroll
    for (int j = 0; j < 4; ++j) {
      float lv = __shfl(L[rt][j], l & 48);     // broadcast from lane 16*(l>>4)
      float inv = 1.0f / lv;
      int row = rowbase + rt * 16 + l4 * 4 + j;
      float* po = out + row * DOUT + hb * 128 + lm;
#pragma unroll
      for (int ct = 0; ct < 8; ++ct) po[ct * 16] = O[rt][ct][j] * inv;
    }
  }
}

extern "C" void kernel_launch(void* const* d_in, const int* in_sizes, int n_in,
                              void* d_out, int out_size, void* d_ws, size_t ws_size,
                              hipStream_t stream) {
  const float* x = (const float*)d_in[0];
  const float* ctrs = (const float*)d_in[1];
  const float* values = (const float*)d_in[2];
  const float* s = (const float*)d_in[3];
  float* out = (float*)d_out;
  char* ws = (char*)d_ws;

  hipLaunchKernelGGL(precompute_kernel, dim3(180), dim3(256), 0, stream,
                     ctrs, values, s, ws);
  hipLaunchKernelGGL(attn_kernel, dim3(512), dim3(256), 0, stream,
                     x, s, ws, out);
}

// Round 4
// 140.344 us; speedup vs baseline: 1.4597x; 1.4597x over previous
//
#include <hip/hip_runtime.h>

typedef _Float16 half_t;
typedef half_t f16x8 __attribute__((ext_vector_type(8)));
typedef float f32x4 __attribute__((ext_vector_type(4)));

#define LOG2E 1.44269504088896340736f

// Problem dims (fixed)
#define NROWS 65536
#define DIN   64
#define NCTRS 1024
#define DOUT  256

// Workspace layout (bytes). ONE FRAGMENT = 64 lanes x 16 B = 1024 B.
// (R2/R3 bug: these were 512 B/frag -> csq2 floats aliased Vswz frags; the
//  float mantissa low bits decode as f16 NaN ~3% of the time -> NaN output.)
// Cswz: QK B-frags, fid = c*4 + ct*2 + kt : 128 frags
// Vswz: PV B-frags, fid = c*16 + sl      : 512 frags
// csq2: 1024 floats = (sum_d ctrs^2 s) * LOG2E
#define CSWZ_OFF 0
#define CSWZ_BYTES (128 * 1024)
#define VSWZ_OFF (CSWZ_OFF + CSWZ_BYTES)            // 131072
#define VSWZ_BYTES (512 * 1024)
#define CSQ_OFF  (VSWZ_OFF + VSWZ_BYTES)            // 655360; end 659456

#define VT_STRIDE 260   // 256 + 4 pad
#define CT_STRIDE 68

// ---------------------------------------------------------------------------
// Precompute: one block per 32-center chunk. Coalesced global loads into LDS
// tiles, then frag-layout stores. Fragment layout (A/B symmetric):
//   lane holds [idx = lane&15][k = 8*(lane>>4) + j], j=0..7 (16 B contiguous)
// ---------------------------------------------------------------------------
__global__ __launch_bounds__(256) void precompute_kernel(
    const float* __restrict__ ctrs, const float* __restrict__ values,
    const float* __restrict__ s, char* __restrict__ ws) {
  half_t* Cswz = (half_t*)(ws + CSWZ_OFF);
  half_t* Vswz = (half_t*)(ws + VSWZ_OFF);
  float* csq2 = (float*)(ws + CSQ_OFF);

  __shared__ half_t Vt[32 * VT_STRIDE];  // 32 x 256 (padded)
  __shared__ half_t Ct[32 * CT_STRIDE];  // 32 x 64  (padded)

  const int c = blockIdx.x, tid = threadIdx.x;

  for (int i = tid; i < 32 * 256; i += 256) {
    int r = i >> 8, col = i & 255;
    Vt[r * VT_STRIDE + col] = (half_t)values[(c * 32 + r) * DOUT + col];
  }
  for (int i = tid; i < 32 * 64; i += 256) {
    int r = i >> 6, col = i & 63;
    Ct[r * CT_STRIDE + col] = (half_t)ctrs[(c * 32 + r) * DIN + col];
  }
  if (tid < 32) {
    int k = c * 32 + tid;
    float acc = 0.0f;
    for (int d = 0; d < DIN; ++d) {
      float cv = ctrs[k * DIN + d];
      acc = fmaf(cv * cv, s[d], acc);
    }
    csq2[k] = acc * LOG2E;
  }
  __syncthreads();

  const int w = tid >> 6, l = tid & 63, l4 = l >> 4, lm = l & 15;

  {  // Cswz: frag f = w; ct = f>>1, kt = f&1
    int ct = w >> 1, kt = w & 1;
    f16x8 v;
#pragma unroll
    for (int j = 0; j < 8; ++j)
      v[j] = Ct[(ct * 16 + lm) * CT_STRIDE + kt * 32 + l4 * 8 + j];
    *(f16x8*)(Cswz + ((c * 4 + w) * 64 + l) * 8) = v;
  }
#pragma unroll
  for (int q = 0; q < 4; ++q) {  // Vswz: 16 frags, 4 per wave
    int sl = w * 4 + q;
    f16x8 v;
#pragma unroll
    for (int j = 0; j < 8; ++j)
      v[j] = Vt[(l4 * 8 + j) * VT_STRIDE + sl * 16 + lm];
    *(f16x8*)(Vswz + ((c * 16 + sl) * 64 + l) * 8) = v;
  }
}

// ---------------------------------------------------------------------------
// Fused kernel, TWO-PASS softmax (no online rescale, no per-chunk shuffles):
//   pass 1: per-lane running max of scores over all 32 chunks, one
//           4-shuffle reduce at the end -> exact row max m.
//   pass 2: recompute scores (bitwise identical), p = exp2(s - m) <= 1,
//           P -> per-wave LDS -> A-frag, PV MFMA; row-sum L via ones column.
// Block = 128 rows x 256 cols (4 waves x 32 rows). Zero barriers.
// scores = (2*cross - csq)*log2e  (x^2 term cancels in softmax).
// ---------------------------------------------------------------------------
__global__ __launch_bounds__(256, 2) void attn_kernel(
    const float* __restrict__ x, const float* __restrict__ s,
    const char* __restrict__ ws, float* __restrict__ out) {
  const half_t* Cswz = (const half_t*)(ws + CSWZ_OFF);
  const half_t* Vswz = (const half_t*)(ws + VSWZ_OFF);
  const float* csq2 = (const float*)(ws + CSQ_OFF);
  const f16x8* cbase = (const f16x8*)Cswz;
  const f16x8* vbase = (const f16x8*)Vswz;

  __shared__ half_t Plds[4 * 32 * 40];  // per-wave P (pad 40): 10240 B

  const int tid = threadIdx.x;
  const int w = tid >> 6, l = tid & 63, l4 = l >> 4, lm = l & 15;
  const int rowbase = blockIdx.x * 128 + w * 32;

  // ---- A fragments (x*s -> f16) in registers, loaded once
  f16x8 A[2][2];
#pragma unroll
  for (int rt = 0; rt < 2; ++rt) {
#pragma unroll
    for (int kt = 0; kt < 2; ++kt) {
      int din = kt * 32 + l4 * 8;
      const float* src = x + (rowbase + rt * 16 + lm) * DIN + din;
      f16x8 a;
#pragma unroll
      for (int j = 0; j < 8; ++j) a[j] = (half_t)(src[j] * s[din + j]);
      A[rt][kt] = a;
    }
  }

  // ---- all-ones B column tile (col 0), lane-constant
  f16x8 ones;
#pragma unroll
  for (int j = 0; j < 8; ++j) ones[j] = (lm == 0) ? (half_t)1.0f : (half_t)0.0f;

  // ================= PASS 1: row max =================
  float m[2][4];
#pragma unroll
  for (int rt = 0; rt < 2; ++rt)
#pragma unroll
    for (int j = 0; j < 4; ++j) m[rt][j] = -1e30f;

  f16x8 nb0 = cbase[0 * 64 + l], nb1 = cbase[1 * 64 + l];
  f16x8 nb2 = cbase[2 * 64 + l], nb3 = cbase[3 * 64 + l];
  float ncs0 = csq2[lm], ncs1 = csq2[16 + lm];

  for (int c = 0; c < 32; ++c) {
    f16x8 b0 = nb0, b1 = nb1, b2 = nb2, b3 = nb3;
    float cs0 = ncs0, cs1 = ncs1;
    int cn = (c < 31) ? c + 1 : 31;  // depth-1 prefetch
    nb0 = cbase[(cn * 4 + 0) * 64 + l];
    nb1 = cbase[(cn * 4 + 1) * 64 + l];
    nb2 = cbase[(cn * 4 + 2) * 64 + l];
    nb3 = cbase[(cn * 4 + 3) * 64 + l];
    ncs0 = csq2[cn * 32 + lm];
    ncs1 = csq2[cn * 32 + 16 + lm];
#pragma unroll
    for (int rt = 0; rt < 2; ++rt) {
      f32x4 a0 = {0.f, 0.f, 0.f, 0.f}, a1 = {0.f, 0.f, 0.f, 0.f};
      a0 = __builtin_amdgcn_mfma_f32_16x16x32_f16(A[rt][0], b0, a0, 0, 0, 0);
      a0 = __builtin_amdgcn_mfma_f32_16x16x32_f16(A[rt][1], b1, a0, 0, 0, 0);
      a1 = __builtin_amdgcn_mfma_f32_16x16x32_f16(A[rt][0], b2, a1, 0, 0, 0);
      a1 = __builtin_amdgcn_mfma_f32_16x16x32_f16(A[rt][1], b3, a1, 0, 0, 0);
#pragma unroll
      for (int j = 0; j < 4; ++j) {
        float v0 = fmaf(a0[j], 2.0f * LOG2E, -cs0);
        float v1 = fmaf(a1[j], 2.0f * LOG2E, -cs1);
        m[rt][j] = fmaxf(m[rt][j], fmaxf(v0, v1));
      }
    }
  }
  // reduce per-lane maxima -> exact row max (rows live in 16-lane groups)
#pragma unroll
  for (int rt = 0; rt < 2; ++rt)
#pragma unroll
    for (int j = 0; j < 4; ++j) {
      float v = m[rt][j];
      v = fmaxf(v, __shfl_xor(v, 1));
      v = fmaxf(v, __shfl_xor(v, 2));
      v = fmaxf(v, __shfl_xor(v, 4));
      v = fmaxf(v, __shfl_xor(v, 8));
      m[rt][j] = v;
    }

  // ================= PASS 2: exp + PV =================
  f32x4 O[2][16];
  f32x4 L[2];
#pragma unroll
  for (int rt = 0; rt < 2; ++rt) {
    L[rt] = (f32x4){0.f, 0.f, 0.f, 0.f};
#pragma unroll
    for (int u = 0; u < 16; ++u) O[rt][u] = (f32x4){0.f, 0.f, 0.f, 0.f};
  }

  half_t* pw = Plds + w * (32 * 40);  // wave-private P region

  for (int c = 0; c < 32; ++c) {
    f16x8 b0 = cbase[(c * 4 + 0) * 64 + l];
    f16x8 b1 = cbase[(c * 4 + 1) * 64 + l];
    f16x8 b2 = cbase[(c * 4 + 2) * 64 + l];
    f16x8 b3 = cbase[(c * 4 + 3) * 64 + l];
    float cs0 = csq2[c * 32 + lm], cs1 = csq2[c * 32 + 16 + lm];
    f16x8 pa[2];
#pragma unroll
    for (int rt = 0; rt < 2; ++rt) {
      f32x4 a0 = {0.f, 0.f, 0.f, 0.f}, a1 = {0.f, 0.f, 0.f, 0.f};
      a0 = __builtin_amdgcn_mfma_f32_16x16x32_f16(A[rt][0], b0, a0, 0, 0, 0);
      a0 = __builtin_amdgcn_mfma_f32_16x16x32_f16(A[rt][1], b1, a0, 0, 0, 0);
      a1 = __builtin_amdgcn_mfma_f32_16x16x32_f16(A[rt][0], b2, a1, 0, 0, 0);
      a1 = __builtin_amdgcn_mfma_f32_16x16x32_f16(A[rt][1], b3, a1, 0, 0, 0);
#pragma unroll
      for (int j = 0; j < 4; ++j) {
        // bitwise-identical recompute of pass-1 scores => s - m <= 0
        float v0 = fmaf(a0[j], 2.0f * LOG2E, -cs0) - m[rt][j];
        float v1 = fmaf(a1[j], 2.0f * LOG2E, -cs1) - m[rt][j];
        float p0 = __builtin_amdgcn_exp2f(v0);
        float p1 = __builtin_amdgcn_exp2f(v1);
        int pr = (rt * 16 + l4 * 4 + j) * 40 + lm;
        pw[pr] = (half_t)p0;
        pw[pr + 16] = (half_t)p1;
      }
      // P back as A-operand (same-wave LDS; DS pipe is in-order per wave)
      pa[rt] = *(const f16x8*)(pw + (rt * 16 + lm) * 40 + l4 * 8);
    }
#pragma unroll
    for (int u = 0; u < 16; ++u) {
      f16x8 vb = vbase[(c * 16 + u) * 64 + l];
      O[0][u] = __builtin_amdgcn_mfma_f32_16x16x32_f16(pa[0], vb, O[0][u], 0, 0, 0);
      O[1][u] = __builtin_amdgcn_mfma_f32_16x16x32_f16(pa[1], vb, O[1][u], 0, 0, 0);
    }
    L[0] = __builtin_amdgcn_mfma_f32_16x16x32_f16(pa[0], ones, L[0], 0, 0, 0);
    L[1] = __builtin_amdgcn_mfma_f32_16x16x32_f16(pa[1], ones, L[1], 0, 0, 0);
  }

  // ---- epilogue: normalize (row sum = col 0 of L tile, lanes lm==0)
#pragma unroll
  for (int rt = 0; rt < 2; ++rt) {
#pragma unroll
    for (int j = 0; j < 4; ++j) {
      float lv = __shfl(L[rt][j], l & 48);  // broadcast from lane 16*l4
      float inv = 1.0f / fmaxf(lv, 1e-30f);
      int row = rowbase + rt * 16 + l4 * 4 + j;
      float* po = out + row * DOUT + lm;
#pragma unroll
      for (int ct = 0; ct < 16; ++ct) po[ct * 16] = O[rt][ct][j] * inv;
    }
  }
}

extern "C" void kernel_launch(void* const* d_in, const int* in_sizes, int n_in,
                              void* d_out, int out_size, void* d_ws, size_t ws_size,
                              hipStream_t stream) {
  const float* x = (const float*)d_in[0];
  const float* ctrs = (const float*)d_in[1];
  const float* values = (const float*)d_in[2];
  const float* s = (const float*)d_in[3];
  float* out = (float*)d_out;
  char* ws = (char*)d_ws;

  hipLaunchKernelGGL(precompute_kernel, dim3(32), dim3(256), 0, stream,
                     ctrs, values, s, ws);
  hipLaunchKernelGGL(attn_kernel, dim3(512), dim3(256), 0, stream,
                     x, s, ws, out);
}